// Round 5
// baseline (135.998 us; speedup 1.0000x reference)
//
#include <hip/hip_runtime.h>

// MPS classifier: logits[b,o] = (v/||v||)·cls[o] + log||v||,
//   v = head0(b) · M_1(b) · ... · M_783(b),  M_n = A_n + x[b,n]*(B_n - A_n).
// Chain is associative; normalizations telescope.
//   K0: repack cores -> per-site float4 (A_2q, A_2q+1, D_2q, D_2q+1) pairs
//   K1: per (sample, chunk): 2 lanes own 5 rows each of the running 10x10
//       product, kept as float2 pairs; matmul via v_pk_fma_f32 (2 FMA/instr)
//       with op_sel broadcasting src.lo/src.hi. Weights+x staged in LDS.
//   K2: per-sample combine over chunks: depth-8 prefetch ring (static idx),
//       Frobenius renorm deferred to every 8th chunk (P's are pre-normalized
//       so |v| only shrinks; no overflow, underflow bounded ~1e-6/8 chunks).

typedef float f32x2 __attribute__((ext_vector_type(2)));

constexpr int Bsz  = 2048;
constexpr int Nn   = 784;
constexpr int NS   = 783;
constexpr int MAXL = 16;

// packed fp32 helpers (VOP3P). D = S0*S1 + S2.
#define PK_FMA(d, a, b, c) \
  asm("v_pk_fma_f32 %0, %1, %2, %3" : "=v"(d) : "v"(a), "v"(b), "v"(c))
// dst += m * src.lo  (both result halves use src's LOW half)
#define PK_FMA_ACC_LO(d, m, s) \
  asm("v_pk_fma_f32 %0, %1, %2, %0 op_sel:[0,0,0] op_sel_hi:[1,0,1]" \
      : "+v"(d) : "v"(m), "v"(s))
// dst += m * src.hi  (both result halves use src's HIGH half)
#define PK_FMA_ACC_HI(d, m, s) \
  asm("v_pk_fma_f32 %0, %1, %2, %0 op_sel:[0,1,0] op_sel_hi:[1,1,1]" \
      : "+v"(d) : "v"(m), "v"(s))
// dst = m * src.lo
#define PK_MUL_LO(d, m, s) \
  asm("v_pk_mul_f32 %0, %1, %2 op_sel:[0,0] op_sel_hi:[1,0]" \
      : "=v"(d) : "v"(m), "v"(s))

// ---------------- K0: repack weights ----------------
// in : cores[k][i][f][j]  (k*200 + i*20 + f*10 + j), f=0 -> A, f=1 -> B
// out: float4 rw4[k*50 + i*5 + q] = (A[i][2q], A[i][2q+1], D[i][2q], D[i][2q+1])
__global__ void repack_kernel(const float* __restrict__ cores,
                              float4* __restrict__ rw4) {
    int tid = blockIdx.x * blockDim.x + threadIdx.x;
    if (tid >= NS * 50) return;
    int k = tid / 50;
    int e = tid - k * 50;
    int i = e / 5, q = e - i * 5;
    const float a0 = cores[k * 200 + i * 20 + 2 * q];
    const float a1 = cores[k * 200 + i * 20 + 2 * q + 1];
    const float b0 = cores[k * 200 + i * 20 + 10 + 2 * q];
    const float b1 = cores[k * 200 + i * 20 + 10 + 2 * q + 1];
    float4 w;
    w.x = a0; w.y = a1; w.z = b0 - a0; w.w = b1 - a1;
    rw4[k * 50 + i * 5 + q] = w;
}

// ---------------- K1: dst(5x10) = src(5x10) * M(site) via pk_fma ----------
__device__ __forceinline__ void site_step(const float4* __restrict__ wp,
                                          const f32x2 x2,
                                          const f32x2 (&src)[5][5],
                                          f32x2 (&dst)[5][5]) {
#pragma unroll
    for (int ip = 0; ip < 5; ++ip) {
        f32x2 m[5];
        // M row 2*ip: blend pairs
#pragma unroll
        for (int qq = 0; qq < 5; ++qq) {
            const float4 w = wp[(2 * ip) * 5 + qq];
            const f32x2 a  = {w.x, w.y};
            const f32x2 dd = {w.z, w.w};
            PK_FMA(m[qq], dd, x2, a);
        }
        if (ip == 0) {
#pragma unroll
            for (int r = 0; r < 5; ++r) {
                const f32x2 s2 = src[r][0];
#pragma unroll
                for (int qq = 0; qq < 5; ++qq) PK_MUL_LO(dst[r][qq], m[qq], s2);
            }
        } else {
#pragma unroll
            for (int r = 0; r < 5; ++r) {
                const f32x2 s2 = src[r][ip];
#pragma unroll
                for (int qq = 0; qq < 5; ++qq) PK_FMA_ACC_LO(dst[r][qq], m[qq], s2);
            }
        }
        // M row 2*ip+1
#pragma unroll
        for (int qq = 0; qq < 5; ++qq) {
            const float4 w = wp[(2 * ip + 1) * 5 + qq];
            const f32x2 a  = {w.x, w.y};
            const f32x2 dd = {w.z, w.w};
            PK_FMA(m[qq], dd, x2, a);
        }
#pragma unroll
        for (int r = 0; r < 5; ++r) {
            const f32x2 s2 = src[r][ip];
#pragma unroll
            for (int qq = 0; qq < 5; ++qq) PK_FMA_ACC_HI(dst[r][qq], m[qq], s2);
        }
    }
}

__global__ __launch_bounds__(256, 3) void chunk_kernel(
    const float* __restrict__ x, const float4* __restrict__ rw4,
    float* __restrict__ pbuf, float* __restrict__ lbuf, int L) {
    __shared__ float4 s_w[MAXL * 50];   // chunk weights, paired layout
    __shared__ float  s_x[128 * 17];    // x slice, stride 17

    const int c   = blockIdx.y;         // chunk (y so same-c blocks are adjacent)
    const int n0  = 1 + c * L;
    const int n1  = min(n0 + L, Nn);
    const int ns  = n1 - n0;
    const int tid = (int)threadIdx.x;
    const int b0  = (int)blockIdx.x * 128;

    const float4* gw = rw4 + (size_t)(n0 - 1) * 50;
    for (int idx = tid; idx < ns * 50; idx += 256) s_w[idx] = gw[idx];
    for (int e = tid; e < ns * 128; e += 256) {
        int k = e >> 7, bl = e & 127;
        s_x[bl * 17 + k] = x[(size_t)(b0 + bl) * Nn + n0 + k];
    }
    __syncthreads();

    const int h = tid & 1;
    const int u = tid >> 1;
    const int b = b0 + u;
    const float* __restrict__ xs = s_x + u * 17;

    f32x2 p[5][5], q2[5][5];
    {   // first site: P = M (rows 5h..5h+4)
        const float xv = xs[0];
        const f32x2 x2 = {xv, xv};
#pragma unroll
        for (int r = 0; r < 5; ++r) {
            const float4* wr = s_w + (5 * h + r) * 5;
#pragma unroll
            for (int qq = 0; qq < 5; ++qq) {
                const float4 w = wr[qq];
                const f32x2 a  = {w.x, w.y};
                const f32x2 dd = {w.z, w.w};
                PK_FMA(p[r][qq], dd, x2, a);
            }
        }
    }
    int k = 1;
    const float4* wp = s_w + 50;
    while (k + 1 < ns) {
        const f32x2 xa = {xs[k], xs[k]};
        const f32x2 xc = {xs[k + 1], xs[k + 1]};
        site_step(wp,      xa, p, q2);
        site_step(wp + 50, xc, q2, p);
        wp += 100;
        k  += 2;
    }
    if (k < ns) {   // even-ns tail
        const f32x2 xa = {xs[k], xs[k]};
        site_step(wp, xa, p, q2);
#pragma unroll
        for (int r = 0; r < 5; ++r)
#pragma unroll
            for (int qq = 0; qq < 5; ++qq) p[r][qq] = q2[r][qq];
    }

    // Frobenius renorm once per chunk (pair-reduce, then shfl across halves)
    f32x2 ss = {0.f, 0.f};
#pragma unroll
    for (int r = 0; r < 5; ++r)
#pragma unroll
        for (int qq = 0; qq < 5; ++qq) PK_FMA(ss, p[r][qq], p[r][qq], ss);
    float s = ss.x + ss.y;
    s += __shfl_xor(s, 1);
    s = fmaxf(s, 1e-30f);
    const float rin = rsqrtf(s);
    if (h == 0) lbuf[(size_t)c * Bsz + b] = 0.5f * __logf(s);

    // store chunk-major-in-b for coalesced K2 reads
#pragma unroll
    for (int r = 0; r < 5; ++r) {
        const int i = 5 * h + r;
#pragma unroll
        for (int qq = 0; qq < 5; ++qq) {
            pbuf[(size_t)(c * 100 + i * 10 + 2 * qq)     * Bsz + b] = p[r][qq].x * rin;
            pbuf[(size_t)(c * 100 + i * 10 + 2 * qq + 1) * Bsz + b] = p[r][qq].y * rin;
        }
    }
}

// ---------------- K2: combine chunks + logits (16 lanes per sample) --------
__global__ __launch_bounds__(256, 2) void combine_kernel(
    const float* __restrict__ x, const float* __restrict__ core0,
    const float* __restrict__ cls, const float* __restrict__ pbuf,
    const float* __restrict__ lbuf, float* __restrict__ out, int C) {
    const int tid   = (int)threadIdx.x;
    const int j     = tid & 15;
    const int jj    = (j < 10) ? j : 9;
    const int gbase = tid & 48;
    const int b     = blockIdx.x * 16 + (tid >> 4);

    float v[10];
    const float x0 = x[(size_t)b * Nn];
#pragma unroll
    for (int i = 0; i < 10; ++i) {
        const float c0 = core0[i], c1 = core0[10 + i];
        v[i] = fmaf(x0, c1 - c0, c0);
    }

    // depth-8 prefetch ring, statically indexed
    float w[8][10];
#pragma unroll
    for (int k8 = 0; k8 < 8; ++k8) {
        if (k8 < C) {
            const float* pn = pbuf + (size_t)(k8 * 100 + jj) * Bsz + b;
#pragma unroll
            for (int i = 0; i < 10; ++i) w[k8][i] = pn[(size_t)(i * 10) * Bsz];
        }
    }

    float llog = 0.f;
    for (int cg = 0; cg < C; cg += 8) {
#pragma unroll
        for (int k8 = 0; k8 < 8; ++k8) {
            const int c = cg + k8;
            if (c >= C) break;
            float acc = 0.f;
#pragma unroll
            for (int i = 0; i < 10; ++i) acc = fmaf(v[i], w[k8][i], acc);
            if (j >= 10) acc = 0.f;
            llog += lbuf[(size_t)c * Bsz + b];
            if (k8 == 7 || c == C - 1) {   // deferred renorm
                float s = acc * acc;
                s += __shfl_xor(s, 1);
                s += __shfl_xor(s, 2);
                s += __shfl_xor(s, 4);
                s += __shfl_xor(s, 8);
                s = fmaxf(s, 1e-30f);
                llog += 0.5f * __logf(s);
                acc *= rsqrtf(s);
            }
#pragma unroll
            for (int i = 0; i < 10; ++i) v[i] = __shfl(acc, gbase + i);
            if (c + 8 < C) {               // refill the slot just consumed
                const float* pn = pbuf + (size_t)((c + 8) * 100 + jj) * Bsz + b;
#pragma unroll
                for (int i = 0; i < 10; ++i) w[k8][i] = pn[(size_t)(i * 10) * Bsz];
            }
        }
    }

    if (j < 10) {
        float acc = llog;
#pragma unroll
        for (int i = 0; i < 10; ++i) acc = fmaf(v[i], cls[j * 10 + i], acc);
        out[(size_t)b * 10 + j] = acc;
    }
}

// ---------------- launch ----------------
extern "C" void kernel_launch(void* const* d_in, const int* in_sizes, int n_in,
                              void* d_out, int out_size, void* d_ws, size_t ws_size,
                              hipStream_t stream) {
    const float* x     = (const float*)d_in[0];
    const float* core0 = (const float*)d_in[1];
    const float* cores = (const float*)d_in[2];
    const float* cls   = (const float*)d_in[3];
    float* out = (float*)d_out;

    float4* rw4 = (float4*)d_ws;                    // NS*50 float4
    size_t off = ((size_t)NS * 200 * 4 + 255) & ~(size_t)255;
    size_t per_chunk = (size_t)100 * Bsz * 4 + (size_t)Bsz * 4;  // P + log
    size_t avail = ws_size > off ? ws_size - off : 0;
    int C = (int)(avail / per_chunk);
    if (C > 61) C = 61;
    if (C < 1)  C = 1;
    int L = (NS + C - 1) / C;
    C = (NS + L - 1) / L;                           // tighten
    float* pbuf = (float*)((char*)d_ws + off);
    float* lbuf = pbuf + (size_t)C * 100 * Bsz;

    hipLaunchKernelGGL(repack_kernel, dim3((NS * 50 + 255) / 256), dim3(256),
                       0, stream, cores, rw4);
    hipLaunchKernelGGL(chunk_kernel, dim3(Bsz / 128, C), dim3(256),
                       0, stream, x, rw4, pbuf, lbuf, L);
    hipLaunchKernelGGL(combine_kernel, dim3(Bsz / 16), dim3(256),
                       0, stream, x, core0, cls, pbuf, lbuf, out, C);
}

// Round 6
// 95.049 us; speedup vs baseline: 1.4308x; 1.4308x over previous
//
#include <hip/hip_runtime.h>

// MPS classifier: logits[b,o] = (v/||v||)·cls[o] + log||v||,
//   v = head0(b) · M_1(b) · ... · M_783(b),  M_n = A_n + x[b,n]*(B_n - A_n).
// Chain associative; normalizations telescope.
//   K0: repack cores -> per-site float4 (A_2q, A_2q+1, D_2q, D_2q+1)
//   K1: per (2 samples, chunk) unit of 2 lanes: lane h owns rows 5h..5h+4 of
//       BOTH samples' running 10x10 products (f32x2 pairs, v_pk_fma_f32).
//       2 samples/lane amortizes the 50 LDS M-reads/site over 2 products.
//   K2: pbuf laid out [chunk][sample][100] -> per-sample contiguous 400 B;
//       depth-8 prefetch ring; renorm deferred to every 8th chunk.

typedef float f32x2 __attribute__((ext_vector_type(2)));

constexpr int Bsz  = 2048;
constexpr int Nn   = 784;
constexpr int NS   = 783;
constexpr int MAXL = 16;

// packed fp32 helpers (VOP3P). D = S0*S1 + S2.
#define PK_FMA(d, a, b, c) \
  asm("v_pk_fma_f32 %0, %1, %2, %3" : "=v"(d) : "v"(a), "v"(b), "v"(c))
#define PK_FMA_ACC_LO(d, m, s) \
  asm("v_pk_fma_f32 %0, %1, %2, %0 op_sel:[0,0,0] op_sel_hi:[1,0,1]" \
      : "+v"(d) : "v"(m), "v"(s))
#define PK_FMA_ACC_HI(d, m, s) \
  asm("v_pk_fma_f32 %0, %1, %2, %0 op_sel:[0,1,0] op_sel_hi:[1,1,1]" \
      : "+v"(d) : "v"(m), "v"(s))
#define PK_MUL_LO(d, m, s) \
  asm("v_pk_mul_f32 %0, %1, %2 op_sel:[0,0] op_sel_hi:[1,0]" \
      : "=v"(d) : "v"(m), "v"(s))

// ---------------- K0: repack weights ----------------
__global__ void repack_kernel(const float* __restrict__ cores,
                              float4* __restrict__ rw4) {
    int tid = blockIdx.x * blockDim.x + threadIdx.x;
    if (tid >= NS * 50) return;
    int k = tid / 50;
    int e = tid - k * 50;
    int i = e / 5, q = e - i * 5;
    const float a0 = cores[k * 200 + i * 20 + 2 * q];
    const float a1 = cores[k * 200 + i * 20 + 2 * q + 1];
    const float b0 = cores[k * 200 + i * 20 + 10 + 2 * q];
    const float b1 = cores[k * 200 + i * 20 + 10 + 2 * q + 1];
    float4 w;
    w.x = a0; w.y = a1; w.z = b0 - a0; w.w = b1 - a1;
    rw4[k * 50 + i * 5 + q] = w;
}

// ---------------- K1: two samples' dst = src * M(site) -------------------
__device__ __forceinline__ void site_step2(const float4* __restrict__ wp,
                                           const f32x2 xA, const f32x2 xB,
                                           const f32x2 (&sA)[5][5],
                                           const f32x2 (&sB)[5][5],
                                           f32x2 (&dA)[5][5],
                                           f32x2 (&dB)[5][5]) {
#pragma unroll
    for (int ip = 0; ip < 5; ++ip) {
#pragma unroll
        for (int qq = 0; qq < 5; ++qq) {
            const float4 w0 = wp[(2 * ip) * 5 + qq];
            const float4 w1 = wp[(2 * ip + 1) * 5 + qq];
            const f32x2 a0 = {w0.x, w0.y}, d0 = {w0.z, w0.w};
            const f32x2 a1 = {w1.x, w1.y}, d1 = {w1.z, w1.w};
            f32x2 mA0, mA1, mB0, mB1;
            PK_FMA(mA0, d0, xA, a0);
            PK_FMA(mA1, d1, xA, a1);
            PK_FMA(mB0, d0, xB, a0);
            PK_FMA(mB1, d1, xB, a1);
            if (ip == 0) {
#pragma unroll
                for (int r = 0; r < 5; ++r) {
                    PK_MUL_LO(dA[r][qq], mA0, sA[r][0]);
                    PK_FMA_ACC_HI(dA[r][qq], mA1, sA[r][0]);
                    PK_MUL_LO(dB[r][qq], mB0, sB[r][0]);
                    PK_FMA_ACC_HI(dB[r][qq], mB1, sB[r][0]);
                }
            } else {
#pragma unroll
                for (int r = 0; r < 5; ++r) {
                    PK_FMA_ACC_LO(dA[r][qq], mA0, sA[r][ip]);
                    PK_FMA_ACC_HI(dA[r][qq], mA1, sA[r][ip]);
                    PK_FMA_ACC_LO(dB[r][qq], mB0, sB[r][ip]);
                    PK_FMA_ACC_HI(dB[r][qq], mB1, sB[r][ip]);
                }
            }
        }
    }
}

__global__ __launch_bounds__(256, 2) void chunk_kernel(
    const float* __restrict__ x, const float4* __restrict__ rw4,
    float* __restrict__ pbuf, float* __restrict__ lbuf, int L) {
    __shared__ float4 s_w[MAXL * 50];   // chunk weights, paired layout
    __shared__ float  s_x[256 * 17];    // x slice for 256 samples, stride 17

    const int c   = blockIdx.y;
    const int n0  = 1 + c * L;
    const int n1  = min(n0 + L, Nn);
    const int ns  = n1 - n0;
    const int tid = (int)threadIdx.x;
    const int b0  = (int)blockIdx.x * 256;

    const float4* gw = rw4 + (size_t)(n0 - 1) * 50;
    for (int idx = tid; idx < ns * 50; idx += 256) s_w[idx] = gw[idx];
    for (int e = tid; e < 256 * 16; e += 256) {
        int bl = e >> 4, k = e & 15;
        if (k < ns)
            s_x[bl * 17 + k] = x[(size_t)(b0 + bl) * Nn + n0 + k];
    }
    __syncthreads();

    const int h  = tid & 1;
    const int u  = tid >> 1;            // unit 0..127
    const int bA = b0 + u;
    const int bB = b0 + 128 + u;
    const float* __restrict__ xsA = s_x + u * 17;
    const float* __restrict__ xsB = s_x + (128 + u) * 17;

    f32x2 pA[5][5], pB[5][5], qA[5][5], qB[5][5];
    {   // first site: P = M (rows 5h..5h+4)
        const f32x2 xA = {xsA[0], xsA[0]};
        const f32x2 xB = {xsB[0], xsB[0]};
#pragma unroll
        for (int r = 0; r < 5; ++r)
#pragma unroll
            for (int qq = 0; qq < 5; ++qq) {
                const float4 w = s_w[(5 * h + r) * 5 + qq];
                const f32x2 a = {w.x, w.y}, dd = {w.z, w.w};
                PK_FMA(pA[r][qq], dd, xA, a);
                PK_FMA(pB[r][qq], dd, xB, a);
            }
    }
    int k = 1;
    const float4* wp = s_w + 50;
    while (k + 1 < ns) {
        {
            const f32x2 xA = {xsA[k], xsA[k]}, xB = {xsB[k], xsB[k]};
            site_step2(wp, xA, xB, pA, pB, qA, qB);
        }
        {
            const f32x2 xA = {xsA[k + 1], xsA[k + 1]}, xB = {xsB[k + 1], xsB[k + 1]};
            site_step2(wp + 50, xA, xB, qA, qB, pA, pB);
        }
        wp += 100;
        k  += 2;
    }
    if (k < ns) {   // even-ns tail
        const f32x2 xA = {xsA[k], xsA[k]}, xB = {xsB[k], xsB[k]};
        site_step2(wp, xA, xB, pA, pB, qA, qB);
#pragma unroll
        for (int r = 0; r < 5; ++r)
#pragma unroll
            for (int qq = 0; qq < 5; ++qq) { pA[r][qq] = qA[r][qq]; pB[r][qq] = qB[r][qq]; }
    }

    // Frobenius renorm per sample (2-lane reduce via shfl_xor lane-pair)
    f32x2 sa = {0.f, 0.f}, sb = {0.f, 0.f};
#pragma unroll
    for (int r = 0; r < 5; ++r)
#pragma unroll
        for (int qq = 0; qq < 5; ++qq) {
            PK_FMA(sa, pA[r][qq], pA[r][qq], sa);
            PK_FMA(sb, pB[r][qq], pB[r][qq], sb);
        }
    float ssA = sa.x + sa.y;  ssA += __shfl_xor(ssA, 1);
    float ssB = sb.x + sb.y;  ssB += __shfl_xor(ssB, 1);
    ssA = fmaxf(ssA, 1e-30f); ssB = fmaxf(ssB, 1e-30f);
    const float rinA = rsqrtf(ssA), rinB = rsqrtf(ssB);
    if (h == 0) {
        lbuf[(size_t)c * Bsz + bA] = 0.5f * __logf(ssA);
        lbuf[(size_t)c * Bsz + bB] = 0.5f * __logf(ssB);
    }

    // store per-sample CONTIGUOUS 100-float blocks: pbuf[(c*Bsz + b)*100 + e]
    {
        float* dA = pbuf + ((size_t)c * Bsz + bA) * 100;
        float* dB = pbuf + ((size_t)c * Bsz + bB) * 100;
#pragma unroll
        for (int r = 0; r < 5; ++r)
#pragma unroll
            for (int qq = 0; qq < 5; ++qq) {
                float2 vA; vA.x = pA[r][qq].x * rinA; vA.y = pA[r][qq].y * rinA;
                float2 vB; vB.x = pB[r][qq].x * rinB; vB.y = pB[r][qq].y * rinB;
                *(float2*)(dA + (5 * h + r) * 10 + 2 * qq) = vA;
                *(float2*)(dB + (5 * h + r) * 10 + 2 * qq) = vB;
            }
    }
}

// ---------------- K2: combine chunks + logits (16 lanes per sample) --------
__global__ __launch_bounds__(256, 2) void combine_kernel(
    const float* __restrict__ x, const float* __restrict__ core0,
    const float* __restrict__ cls, const float* __restrict__ pbuf,
    const float* __restrict__ lbuf, float* __restrict__ out, int C) {
    const int tid   = (int)threadIdx.x;
    const int j     = tid & 15;
    const int jj    = (j < 10) ? j : 9;
    const int gbase = tid & 48;
    const int b     = blockIdx.x * 16 + (tid >> 4);

    float v[10];
    const float x0 = x[(size_t)b * Nn];
#pragma unroll
    for (int i = 0; i < 10; ++i) {
        const float c0 = core0[i], c1 = core0[10 + i];
        v[i] = fmaf(x0, c1 - c0, c0);
    }

    // depth-8 prefetch ring, statically indexed; per-chunk data contiguous
    float w[8][10];
#pragma unroll
    for (int k8 = 0; k8 < 8; ++k8) {
        if (k8 < C) {
            const float* pn = pbuf + ((size_t)k8 * Bsz + b) * 100 + jj;
#pragma unroll
            for (int i = 0; i < 10; ++i) w[k8][i] = pn[i * 10];
        }
    }

    float llog = 0.f;
    for (int cg = 0; cg < C; cg += 8) {
#pragma unroll
        for (int k8 = 0; k8 < 8; ++k8) {
            const int c = cg + k8;
            if (c >= C) break;
            float acc = 0.f;
#pragma unroll
            for (int i = 0; i < 10; ++i) acc = fmaf(v[i], w[k8][i], acc);
            if (j >= 10) acc = 0.f;
            llog += lbuf[(size_t)c * Bsz + b];
            if (k8 == 7 || c == C - 1) {   // deferred renorm
                float s = acc * acc;
                s += __shfl_xor(s, 1);
                s += __shfl_xor(s, 2);
                s += __shfl_xor(s, 4);
                s += __shfl_xor(s, 8);
                s = fmaxf(s, 1e-30f);
                llog += 0.5f * __logf(s);
                acc *= rsqrtf(s);
            }
#pragma unroll
            for (int i = 0; i < 10; ++i) v[i] = __shfl(acc, gbase + i);
            if (c + 8 < C) {               // refill the slot just consumed
                const float* pn = pbuf + ((size_t)(c + 8) * Bsz + b) * 100 + jj;
#pragma unroll
                for (int i = 0; i < 10; ++i) w[k8][i] = pn[i * 10];
            }
        }
    }

    if (j < 10) {
        float acc = llog;
#pragma unroll
        for (int i = 0; i < 10; ++i) acc = fmaf(v[i], cls[j * 10 + i], acc);
        out[(size_t)b * 10 + j] = acc;
    }
}

// ---------------- launch ----------------
extern "C" void kernel_launch(void* const* d_in, const int* in_sizes, int n_in,
                              void* d_out, int out_size, void* d_ws, size_t ws_size,
                              hipStream_t stream) {
    const float* x     = (const float*)d_in[0];
    const float* core0 = (const float*)d_in[1];
    const float* cores = (const float*)d_in[2];
    const float* cls   = (const float*)d_in[3];
    float* out = (float*)d_out;

    float4* rw4 = (float4*)d_ws;                    // NS*50 float4
    size_t off = ((size_t)NS * 200 * 4 + 255) & ~(size_t)255;
    size_t per_chunk = (size_t)100 * Bsz * 4 + (size_t)Bsz * 4;  // P + log
    size_t avail = ws_size > off ? ws_size - off : 0;
    int C = (int)(avail / per_chunk);
    if (C > 61) C = 61;
    if (C < 1)  C = 1;
    int L = (NS + C - 1) / C;
    if (L > MAXL) L = MAXL;                         // LDS capacity guard
    C = (NS + L - 1) / L;                           // tighten
    float* pbuf = (float*)((char*)d_ws + off);
    float* lbuf = pbuf + (size_t)C * 100 * Bsz;

    hipLaunchKernelGGL(repack_kernel, dim3((NS * 50 + 255) / 256), dim3(256),
                       0, stream, cores, rw4);
    hipLaunchKernelGGL(chunk_kernel, dim3(Bsz / 256, C), dim3(256),
                       0, stream, x, rw4, pbuf, lbuf, L);
    hipLaunchKernelGGL(combine_kernel, dim3(Bsz / 16), dim3(256),
                       0, stream, x, core0, cls, pbuf, lbuf, out, C);
}